// Round 10
// baseline (8692.976 us; speedup 1.0000x reference)
//
#include <hip/hip_runtime.h>

// LSTM: S=4096, I=64, H=1024, O=1, fp32.
// Persistent cooperative kernel, 64 blocks x 1024 threads (16 waves).
// R10 theory: step time ~= contention-inflated L3 poll iteration (~800cy,
// FETCH/step => ~6 sweeps/step) + arrival tail over publish lines. Halve
// both: 64 blocks (512 pollers each, half the in-flight atomic loads) and
// 64 coalesced 128B publishes (vs 128x64B).
//   wave w (0..15) owns h index j=16b+w; lane: grp=l>>4 (gate), sl=l&15.
// Weights: two-pass stage via 136KB LDS buffer -> named per-thread regs
// (r9 mechanics); in-loop LDS traffic = h only.
// Protocol (r5/6/9, validated): tagged slots {tag:32|h_bits:32}, relaxed
// agent-scope atomics, tagged double buffer, zero fences, ONE barrier/step,
// wave-0 gather + coalesced line publish. WRITE_SIZE must stay 32768 KB.

#define SEQ_LEN 4096
#define HID 1024
#define NBLK 64
#define TPB 1024
#define HPB 16     // h-indices per block (one per wave)

__device__ __forceinline__ float fast_sigmoid(float x) {
    return __builtin_amdgcn_rcpf(1.0f + __builtin_amdgcn_exp2f(-1.4426950408889634f * x));
}
__device__ __forceinline__ float fast_tanh(float x) {
    return fmaf(-2.0f, __builtin_amdgcn_rcpf(1.0f + __builtin_amdgcn_exp2f(2.8853900817779268f * x)), 1.0f);
}

// ws: unsigned long long slots[2][1024]. {tag<<32 | fp32 bits}. Zero-init:
// buffer0 tag0/val0 == h_0 = 0 (correct); buffer1 receives odd tags.
__global__ void lstm_init_kernel(unsigned long long* ws) {
    int t = threadIdx.x;
    #pragma unroll
    for (int k = 0; k < 8; ++k) ws[t + 256 * k] = 0ull;
}

__global__ __launch_bounds__(TPB, 1) void lstm_persistent_kernel(
    const float* __restrict__ input,   // [4096][64]
    const float* __restrict__ W_ih,    // [4096][64]
    const float* __restrict__ W_hh,    // [4096][1024]
    const float* __restrict__ b_ih,    // [4096]
    const float* __restrict__ b_hh,    // [4096]
    const float* __restrict__ W_lin,   // [1][1024]
    const float* __restrict__ b_lin,   // [1]
    float* __restrict__ out,           // [1]
    unsigned long long* __restrict__ ws)
{
    const int t   = threadIdx.x;
    const int b   = blockIdx.x;
    const int w   = t >> 6;      // wave in block (0..15)
    const int l   = t & 63;      // lane
    const int grp = l >> 4;      // gate q (i,f,g,o)
    const int sl  = l & 15;      // sub-lane within gate group
    const int j   = HPB * b + w; // owned h index
    const int row = grp * HID + j;
    const int th  = t & 511;     // index within half (for staging/poll)
    const int half = t >> 9;     // 0 or 1

    unsigned long long* slot0 = ws;          // even tags
    unsigned long long* slot1 = ws + HID;    // odd tags

    __shared__ float4 wstage[17 * 512];      // 136 KB staging buffer (reused 2x)
    __shared__ float  hs[2][HID];            // double-buffered h (8 KB)
    __shared__ unsigned long long pub[HPB];  // tagged intra-block handoff
    __shared__ float  red[HPB];

    // ---- two-pass weight staging: global -> LDS -> named registers ----
    float4 W0, W1, W2, W3, W4, W5, W6, W7, W8, W9, W10, W11, W12, W13, W14, W15, W16;
    const float4* Whh4 = (const float4*)(W_hh + (size_t)row * HID);
    #pragma unroll
    for (int pass = 0; pass < 2; ++pass) {
        if (half == pass) {
            #pragma unroll
            for (int c = 0; c < 16; ++c)
                wstage[c * 512 + th] = Whh4[sl + 16 * c];   // W_hh[row][64c+4sl..+3]
            wstage[16 * 512 + th] = ((const float4*)(W_ih + (size_t)row * 64))[sl];
        }
        __syncthreads();
        if (half == pass) {
            W0  = wstage[ 0 * 512 + th];  W1  = wstage[ 1 * 512 + th];
            W2  = wstage[ 2 * 512 + th];  W3  = wstage[ 3 * 512 + th];
            W4  = wstage[ 4 * 512 + th];  W5  = wstage[ 5 * 512 + th];
            W6  = wstage[ 6 * 512 + th];  W7  = wstage[ 7 * 512 + th];
            W8  = wstage[ 8 * 512 + th];  W9  = wstage[ 9 * 512 + th];
            W10 = wstage[10 * 512 + th];  W11 = wstage[11 * 512 + th];
            W12 = wstage[12 * 512 + th];  W13 = wstage[13 * 512 + th];
            W14 = wstage[14 * 512 + th];  W15 = wstage[15 * 512 + th];
            W16 = wstage[16 * 512 + th];
        }
        __syncthreads();
    }

    float bias[4];
    #pragma unroll
    for (int q = 0; q < 4; ++q) bias[q] = b_ih[q * HID + j] + b_hh[q * HID + j];
    if (t < HPB) pub[t] = 0ull;

    const float4* xin4 = (const float4*)input;
    float c_state = 0.0f;
    __syncthreads();   // pub initialized

    for (int s = 0; s < SEQ_LEN; ++s) {
        float4 x4 = xin4[s * 16 + sl];   // issue before poll (cacheable)

        // ---- poll: threads 0..511 cover all 1024 slots (2 each) ----
        if (half == 0) {
            unsigned long long* rs = (s & 1) ? slot1 : slot0;
            const unsigned tag = (unsigned)s;
            unsigned long long v0, v1;
            bool r0 = false, r1 = false;
            do {
                if (!r0) { v0 = __hip_atomic_load(&rs[th      ], __ATOMIC_RELAXED, __HIP_MEMORY_SCOPE_AGENT);
                           r0 = ((unsigned)(v0 >> 32) == tag); }
                if (!r1) { v1 = __hip_atomic_load(&rs[th + 512], __ATOMIC_RELAXED, __HIP_MEMORY_SCOPE_AGENT);
                           r1 = ((unsigned)(v1 >> 32) == tag); }
            } while (!(r0 && r1));
            float* hsb = hs[s & 1];
            hsb[th      ] = __uint_as_float((unsigned)(v0 & 0xffffffffull));
            hsb[th + 512] = __uint_as_float((unsigned)(v1 & 0xffffffffull));
        }

        __syncthreads();   // the ONE barrier per step: full h_s staged

        // ---- 68 FMAs: weights from registers, h broadcast-read from LDS ----
        const float4* hs4 = (const float4*)hs[s & 1];
        float a0 = 0.f, a1 = 0.f, a2 = 0.f, a3 = 0.f;
        #define FMA_CHUNK(Wc, c, acc) { float4 h4_ = hs4[16 * (c) + sl];      \
            acc = fmaf((Wc).x, h4_.x, acc); acc = fmaf((Wc).y, h4_.y, acc);   \
            acc = fmaf((Wc).z, h4_.z, acc); acc = fmaf((Wc).w, h4_.w, acc); }
        FMA_CHUNK(W0,  0, a0) FMA_CHUNK(W1,  1, a1)
        FMA_CHUNK(W2,  2, a2) FMA_CHUNK(W3,  3, a3)
        FMA_CHUNK(W4,  4, a0) FMA_CHUNK(W5,  5, a1)
        FMA_CHUNK(W6,  6, a2) FMA_CHUNK(W7,  7, a3)
        FMA_CHUNK(W8,  8, a0) FMA_CHUNK(W9,  9, a1)
        FMA_CHUNK(W10, 10, a2) FMA_CHUNK(W11, 11, a3)
        FMA_CHUNK(W12, 12, a0) FMA_CHUNK(W13, 13, a1)
        FMA_CHUNK(W14, 14, a2) FMA_CHUNK(W15, 15, a3)
        #undef FMA_CHUNK
        a0 = fmaf(W16.x, x4.x, a0); a1 = fmaf(W16.y, x4.y, a1);
        a2 = fmaf(W16.z, x4.z, a2); a3 = fmaf(W16.w, x4.w, a3);
        float acc = (a0 + a1) + (a2 + a3);

        // reduce across 16 lanes of the gate group
        acc += __shfl_xor(acc, 1);
        acc += __shfl_xor(acc, 2);
        acc += __shfl_xor(acc, 4);
        acc += __shfl_xor(acc, 8);

        float gi = __shfl(acc, 0)  + bias[0];
        float gf = __shfl(acc, 16) + bias[1];
        float gg = __shfl(acc, 32) + bias[2];
        float go = __shfl(acc, 48) + bias[3];

        float ig = fast_sigmoid(gi);
        float fg = fast_sigmoid(gf);
        float cg = fast_tanh(gg);
        float og = fast_sigmoid(go);
        c_state  = fmaf(fg, c_state, ig * cg);
        float hn = og * fast_tanh(c_state);

        // ---- intra-block handoff: wave w lane 0 posts tagged hn to LDS ----
        const unsigned ntag = (unsigned)(s + 1);
        if (l == 0) {
            unsigned long long pv = ((unsigned long long)ntag << 32) |
                                    (unsigned long long)__float_as_uint(hn);
            __hip_atomic_store(&pub[w], pv, __ATOMIC_RELAXED, __HIP_MEMORY_SCOPE_WORKGROUP);
        }
        // ---- wave 0 lanes 0..15 gather, publish one 128B contiguous burst ----
        if (w == 0 && l < HPB) {
            unsigned long long pv;
            do {
                pv = __hip_atomic_load(&pub[l], __ATOMIC_RELAXED, __HIP_MEMORY_SCOPE_WORKGROUP);
            } while ((unsigned)(pv >> 32) != ntag);
            unsigned long long* wsl = (s & 1) ? slot0 : slot1;   // buffer (s+1)&1
            __hip_atomic_store(&wsl[HPB * b + l], pv, __ATOMIC_RELAXED, __HIP_MEMORY_SCOPE_AGENT);
        }
        // no trailing barrier: hs double-buffered; slot-tag deps bound skew
    }

    // ---- final projection: h_4096 (tag 4096, even -> slot0) . W_lin + b_lin ----
    if (b == 0) {
        float p = 0.0f;
        if (half == 0) {
            const unsigned tag = (unsigned)SEQ_LEN;
            unsigned long long v0, v1;
            bool r0 = false, r1 = false;
            do {
                if (!r0) { v0 = __hip_atomic_load(&slot0[th      ], __ATOMIC_RELAXED, __HIP_MEMORY_SCOPE_AGENT);
                           r0 = ((unsigned)(v0 >> 32) == tag); }
                if (!r1) { v1 = __hip_atomic_load(&slot0[th + 512], __ATOMIC_RELAXED, __HIP_MEMORY_SCOPE_AGENT);
                           r1 = ((unsigned)(v1 >> 32) == tag); }
            } while (!(r0 && r1));
            p = __uint_as_float((unsigned)(v0 & 0xffffffffull)) * W_lin[th] +
                __uint_as_float((unsigned)(v1 & 0xffffffffull)) * W_lin[th + 512];
        }
        #pragma unroll
        for (int m = 32; m >= 1; m >>= 1) p += __shfl_xor(p, m);
        if (l == 0) red[w] = p;
        __syncthreads();
        if (t == 0) {
            float r = 0.f;
            #pragma unroll
            for (int k = 0; k < HPB; ++k) r += red[k];
            out[0] = r + b_lin[0];
        }
    }
}

extern "C" void kernel_launch(void* const* d_in, const int* in_sizes, int n_in,
                              void* d_out, int out_size, void* d_ws, size_t ws_size,
                              hipStream_t stream) {
    const float* input = (const float*)d_in[0];
    const float* W_ih  = (const float*)d_in[1];
    const float* W_hh  = (const float*)d_in[2];
    const float* b_ih  = (const float*)d_in[3];
    const float* b_hh  = (const float*)d_in[4];
    const float* W_lin = (const float*)d_in[5];
    const float* b_lin = (const float*)d_in[6];
    float* out = (float*)d_out;
    unsigned long long* ws = (unsigned long long*)d_ws;

    hipLaunchKernelGGL(lstm_init_kernel, dim3(1), dim3(256), 0, stream, ws);

    void* args[] = { (void*)&input, (void*)&W_ih, (void*)&W_hh, (void*)&b_ih,
                     (void*)&b_hh, (void*)&W_lin, (void*)&b_lin, (void*)&out, (void*)&ws };
    (void)hipLaunchCooperativeKernel((void*)lstm_persistent_kernel, dim3(NBLK), dim3(TPB),
                                     args, 0, stream);
}